// Round 4
// baseline (240.767 us; speedup 1.0000x reference)
//
#include <hip/hip_runtime.h>
#include <stdint.h>

// DETR PartMap: [2, B, Q, H, W] outside-box masks (1.0 outside, 0.0 inside).
// B=64, Q=300, H=W=40. Output 61.44M fp32 = 245.8 MB -> pure write-BW-bound.
//
// Fused single kernel, dual-stream variant. Each block owns 32 (s,b,q) maps
// (12800 float4). Threads 0..31 compute the 32 box descriptors (40-bit
// x-outside bitmask + y1/y2) into LDS; threads 64..79 build a 16-entry
// float4 bit-pattern table. Then each of the 256 threads runs 25 iterations,
// each iteration storing TWO float4s 6400 apart (maps lm and lm+16):
//   - 2x store ILP, index math (rem/h/w0/addresses) shared across streams
//   - bits->float4 via LDS table lookup (1 ds_read_b128) instead of 8 bfe+cvt
//   - plain dwordx4 stores (NT regressed in R2: bypassing L2 defeats
//     write-combining; the 6.6 TB/s rocclr fill uses plain stores)
// Grid = 1200 blocks -> fully resident (~4.7 blocks/CU), no dispatch tail.

#define B_ 64
#define Q_ 300
#define HM 40
#define WM 40
#define NBOX (2 * B_ * Q_)                   // 38,400 maps
#define MAPS_PER_BLOCK 32
#define NBLOCKS (NBOX / MAPS_PER_BLOCK)      // 1,200
#define F4_PER_MAP 400                       // 40*40/4
#define F4_PER_BLOCK (MAPS_PER_BLOCK * F4_PER_MAP)   // 12,800
#define HALF (F4_PER_BLOCK / 2)              // 6,400
#define ITERS (HALF / 256)                   // 25

typedef float vfloat4 __attribute__((ext_vector_type(4)));

__global__ __launch_bounds__(256) void partmap_fused_kernel(
    const float* __restrict__ obj,
    const float* __restrict__ sub,
    const int*   __restrict__ img,     // [B,2] = (h, w) int32
    vfloat4*     __restrict__ out)
{
    __shared__ uint2   s_d[MAPS_PER_BLOCK];  // {xmask_lo, xmask_hi|y1<<8|y2<<16}
    __shared__ vfloat4 s_tbl[16];            // bit pattern -> float4

    const int tid = threadIdx.x;

    // ---- phase 1a: threads 0..31 compute the 32 box descriptors ----
    if (tid < MAPS_PER_BLOCK) {
        #pragma clang fp contract(off)
        int id = blockIdx.x * MAPS_PER_BLOCK + tid;   // (s*64 + b)*300 + q
        int q  = id % Q_;
        int sb = id / Q_;
        int b  = sb & 63;
        int s  = sb >> 6;

        const float* coord = s ? sub : obj;
        float4 c = ((const float4*)coord)[b * Q_ + q];   // (cx, cy, w, h)

        float sh = (float)img[b * 2 + 0];
        float sw = (float)img[b * 2 + 1];

        // Exact numpy op order: (cx - 0.5*w) * sw / 32, floor, cast. No contraction.
        float x1f = (c.x - 0.5f * c.z) * sw / 32.0f;
        float y1f = (c.y - 0.5f * c.w) * sh / 32.0f;
        float x2f = (c.x + 0.5f * c.z) * sw / 32.0f;
        float y2f = (c.y + 0.5f * c.w) * sh / 32.0f;

        int x1 = (int)floorf(x1f);                // can be negative (>= -20)
        int y1 = (int)floorf(y1f);
        int x2 = min((int)floorf(x2f), WM - 1);   // in [0,39]
        int y2 = min((int)floorf(y2f), HM - 1);   // in [0,39]

        // inside-x bits [x1 .. x2] within 40 bits; outside = complement.
        uint64_t lo = (x1 <= 0) ? ~0ull : ~((1ull << x1) - 1ull);   // x1 <= 39
        uint64_t hi = (1ull << (x2 + 1)) - 1ull;                    // x2 in [0,39]
        uint64_t outside = (~(lo & hi)) & ((1ull << 40) - 1ull);

        uint32_t d0 = (uint32_t)outside;
        uint32_t d1 = ((uint32_t)(outside >> 32) & 0xFFu)
                    | (((uint32_t)y1 & 0xFFu) << 8)
                    | (((uint32_t)y2 & 0xFFu) << 16);
        s_d[tid] = make_uint2(d0, d1);
    }

    // ---- phase 1b: threads 64..79 (wave 1, parallel with 1a) build table ----
    if (tid >= 64 && tid < 80) {
        int t = tid - 64;
        vfloat4 r;
        r.x = (float)( t       & 1);
        r.y = (float)((t >> 1) & 1);
        r.z = (float)((t >> 2) & 1);
        r.w = (float)((t >> 3) & 1);
        s_tbl[t] = r;
    }
    __syncthreads();

    // ---- phase 2: dual-stream 12800 float4 per block ----
    // off = tid + 256*it (< 6400); lm = off/400; rem = off%400, incremental.
    // Stream A -> map lm (offset off), stream B -> map lm+16 (offset off+6400).
    int rem = tid;     // tid < 400
    int lm  = 0;
    vfloat4* __restrict__ p1 = out + (size_t)blockIdx.x * F4_PER_BLOCK + tid;
    vfloat4* __restrict__ p2 = p1 + HALF;

    #pragma unroll
    for (int it = 0; it < ITERS; ++it) {
        uint2 da = s_d[lm];
        uint2 db = s_d[lm + MAPS_PER_BLOCK / 2];

        int h  = rem / 10;                 // rem < 400, magic-mul
        int w0 = (rem - h * 10) * 4;       // bit shift for this float4's 4 cols

        // stream A
        int y1a = (int)(int8_t)(da.y >> 8);
        int y2a = (int)(int8_t)(da.y >> 16);
        int rna = ((h - y1a) | (y2a - h)) >> 31;       // all-ones if h outside
        uint32_t ma = (uint32_t)((((uint64_t)da.y << 32) | da.x) >> w0)
                    | (uint32_t)rna;
        vfloat4 ra = s_tbl[ma & 15u];

        // stream B
        int y1b = (int)(int8_t)(db.y >> 8);
        int y2b = (int)(int8_t)(db.y >> 16);
        int rnb = ((h - y1b) | (y2b - h)) >> 31;
        uint32_t mb = (uint32_t)((((uint64_t)db.y << 32) | db.x) >> w0)
                    | (uint32_t)rnb;
        vfloat4 rb = s_tbl[mb & 15u];

        p1[0] = ra;
        p2[0] = rb;

        rem += 256;
        if (rem >= F4_PER_MAP) { rem -= F4_PER_MAP; ++lm; }
        p1 += 256;
        p2 += 256;
    }
}

extern "C" void kernel_launch(void* const* d_in, const int* in_sizes, int n_in,
                              void* d_out, int out_size, void* d_ws, size_t ws_size,
                              hipStream_t stream) {
    const float* obj = (const float*)d_in[0];   // [B,Q,4] f32
    const float* sub = (const float*)d_in[1];   // [B,Q,4] f32
    const int*   img = (const int*)d_in[2];     // [B,2] int32 (h, w)
    // d_in[3] = mask (bool) — only its shape is used; ignored.
    (void)d_ws; (void)ws_size;

    partmap_fused_kernel<<<dim3(NBLOCKS), dim3(256), 0, stream>>>(
        obj, sub, img, (vfloat4*)d_out);
}